// Round 2
// baseline (17293.721 us; speedup 1.0000x reference)
//
#include <hip/hip_runtime.h>
#include <cstdint>

typedef short short8 __attribute__((ext_vector_type(8)));
typedef float floatx4 __attribute__((ext_vector_type(4)));

#define TS 512
#define BB 64
#define HD 1024
#define MROWS (TS * BB) // 32768

__device__ __forceinline__ unsigned short f2bf(float f) {
    uint32_t u = __float_as_uint(f);
    u += 0x7fffu + ((u >> 16) & 1u); // RNE
    return (unsigned short)(u >> 16);
}

__device__ __forceinline__ void wait_vm0() {
    asm volatile("s_waitcnt vmcnt(0)" ::: "memory");
}

__device__ __forceinline__ unsigned long long ald64(const void* p) {
    return __hip_atomic_load((const unsigned long long*)p, __ATOMIC_RELAXED,
                             __HIP_MEMORY_SCOPE_AGENT);
}

// ---------------- fp32 -> bf16 cast (vectorized) ----------------
__global__ __launch_bounds__(256) void cast_f32_bf16(const float* __restrict__ s,
                                                     unsigned short* __restrict__ d, int n4) {
    int i = blockIdx.x * 256 + threadIdx.x;
    if (i >= n4) return;
    float4 v = ((const float4*)s)[i];
    ushort4 o = make_ushort4(f2bf(v.x), f2bf(v.y), f2bf(v.z), f2bf(v.w));
    ((ushort4*)d)[i] = o;
}

// ---------------- input-projection GEMM ----------------
// C[M,2048] = A[M,K](bf16) * Bt[2048,K]^T + bias ; cols 0..1023 get biasF-1 (BETA), rest biasG
__global__ __launch_bounds__(256) void gemm_bt_bias(
    const unsigned short* __restrict__ A, const unsigned short* __restrict__ Bt,
    const float* __restrict__ biasF, const float* __restrict__ biasG,
    float* __restrict__ C, int M, int K)
{
    const int N = 2048;
    __shared__ unsigned short As[128 * 32];
    __shared__ unsigned short Bs[128 * 32];
    int bm = blockIdx.x * 128, bn = blockIdx.y * 128;
    int th = threadIdx.x;
    int wave = th >> 6, lane = th & 63;
    int lrow = lane & 15, quad = lane >> 4;
    int wm = (wave & 1) * 64, wn = (wave >> 1) * 64;
    const unsigned short* Ag = A + (size_t)bm * K;
    const unsigned short* Bg = Bt + (size_t)bn * K;

    floatx4 acc[4][4];
#pragma unroll
    for (int i = 0; i < 4; ++i)
#pragma unroll
        for (int j = 0; j < 4; ++j) acc[i][j] = (floatx4){0.f, 0.f, 0.f, 0.f};

    for (int k0 = 0; k0 < K; k0 += 32) {
        __syncthreads();
#pragma unroll
        for (int jj = 0; jj < 2; ++jj) {
            int c = jj * 256 + th;          // 512 16B chunks per tile
            int row = c >> 2, kk = c & 3;   // 4 chunks (32 elems) per row
            int ph = (row * 4 + (kk ^ ((row >> 1) & 3))) * 8;
            uint4 va = *(const uint4*)(Ag + (size_t)row * K + k0 + kk * 8);
            uint4 vb = *(const uint4*)(Bg + (size_t)row * K + k0 + kk * 8);
            *(uint4*)(As + ph) = va;
            *(uint4*)(Bs + ph) = vb;
        }
        __syncthreads();
        short8 af[4], bfv[4];
#pragma unroll
        for (int i = 0; i < 4; ++i) {
            int r = wm + i * 16 + lrow;
            af[i] = *(const short8*)(As + (r * 4 + (quad ^ ((r >> 1) & 3))) * 8);
        }
#pragma unroll
        for (int j = 0; j < 4; ++j) {
            int r = wn + j * 16 + lrow;
            bfv[j] = *(const short8*)(Bs + (r * 4 + (quad ^ ((r >> 1) & 3))) * 8);
        }
#pragma unroll
        for (int i = 0; i < 4; ++i)
#pragma unroll
            for (int j = 0; j < 4; ++j)
                acc[i][j] = __builtin_amdgcn_mfma_f32_16x16x32_bf16(af[i], bfv[j], acc[i][j], 0, 0, 0);
    }
#pragma unroll
    for (int j = 0; j < 4; ++j) {
        int col = bn + wn + j * 16 + lrow;
        float bias = (col < 1024) ? (biasF[col] - 1.0f) : biasG[col - 1024];
#pragma unroll
        for (int i = 0; i < 4; ++i) {
            int row0 = bm + wm + i * 16 + quad * 4;
#pragma unroll
            for (int r = 0; r < 4; ++r)
                C[(size_t)(row0 + r) * N + col] = acc[i][j][r] + bias;
        }
    }
}

// ---------------- persistent JANET recurrence ----------------
// 64 WGs x 256 threads. WG w owns hidden cols [16w,16w+16); wave v owns batch rows [16v,16v+16).
// Weights LDS-resident. Fence-FREE cross-WG protocol: h exchange + per-wave flags are
// relaxed agent-scope atomics (sc0/sc1 coherent, L2-bypassing) -> no buffer_wbl2/buffer_inv.
// Release = h stores -> s_waitcnt vmcnt(0) -> flag store. Acquire = flag poll + coherent loads.
__global__ __launch_bounds__(256) void janet_scan(
    const float* __restrict__ P,        // [T*64, 2048]  (pf | pg), bias-BETA folded
    const unsigned short* __restrict__ Rf, // hfW bf16 [1024,1024]
    const unsigned short* __restrict__ Rg, // hgW bf16 [1024,1024]
    const float* __restrict__ hbf, const float* __restrict__ hbg,
    unsigned short* __restrict__ hbuf,  // [2][64][1024] bf16, zeroed
    int* flags,                         // [256] = 64 WG x 4 waves, zeroed
    unsigned short* __restrict__ Ybf,   // layer0 output (bf16) or null
    float* __restrict__ Yf32)           // layer1 output (fp32) or null
{
    __shared__ unsigned short Wl[2][16 * 1024]; // 64 KiB, XOR-swizzled by (n&7)
    const int w = blockIdx.x, th = threadIdx.x;
    const int wave = th >> 6, lane = th & 63;
    const int lrow = lane & 15, quad = lane >> 4;
    const int c0 = w * 16;

    // load weight slices once: 4096 16B chunks (2 gates x 16 rows x 128 chunks)
    for (int c = th; c < 4096; c += 256) {
        int g = c >> 11, n = (c >> 7) & 15, k8 = c & 127;
        const unsigned short* src = (g ? Rg : Rf) + (size_t)(c0 + n) * 1024 + k8 * 8;
        *(uint4*)(&Wl[g][(n * 128 + (k8 ^ (n & 7))) * 8]) = *(const uint4*)src;
    }
    __syncthreads();

    const int col = c0 + lrow;
    const float bF = hbf[col], bG = hbg[col];
    float hr[4] = {0.f, 0.f, 0.f, 0.f};     // fp32 master h, C-layout (b=wave*16+quad*4+r)
    const int myrow = wave * 16 + lrow;      // A-frag batch row
    const int sw = lrow & 7;
    const unsigned short* w0 = &Wl[0][lrow << 10];
    const unsigned short* w1 = &Wl[1][lrow << 10];

    // P prefetch (plain loads; P is read-once, produced by a prior kernel)
    float pf[4], pg[4];
    auto pload = [&](int t, float* pfD, float* pgD) {
        size_t pbase = ((size_t)t * 64 + wave * 16 + quad * 4) * 2048 + col;
#pragma unroll
        for (int r = 0; r < 4; ++r) {
            pfD[r] = P[pbase + (size_t)r * 2048];
            pgD[r] = P[pbase + (size_t)r * 2048 + 1024];
        }
    };
    pload(0, pf, pg);

    for (int t = 0; t < TS; ++t) {
        const unsigned short* hs =
            hbuf + ((size_t)(t & 1) << 16) + ((size_t)myrow << 10) + (quad << 3);

        // coherent h loads, software-pipelined in 4 chunks of 8 k-steps
        unsigned long long b0[16], b1[16];
        auto lchunk = [&](int c, unsigned long long* buf) {
#pragma unroll
            for (int i = 0; i < 8; ++i) {
                const unsigned short* p = hs + ((c * 8 + i) << 5);
                buf[2 * i]     = ald64(p);
                buf[2 * i + 1] = ald64(p + 4);
            }
        };
        floatx4 aF = {0.f, 0.f, 0.f, 0.f}, aG = {0.f, 0.f, 0.f, 0.f};
        auto mchunk = [&](int c, const unsigned long long* buf) {
#pragma unroll
            for (int i = 0; i < 8; ++i) {
                int ks = c * 8 + i;
                union { unsigned long long u[2]; short8 s; } cv;
                cv.u[0] = buf[2 * i]; cv.u[1] = buf[2 * i + 1];
                int koff = ((((ks << 2) + quad) ^ sw) << 3);
                short8 bf_ = *(const short8*)(w0 + koff);
                short8 bg_ = *(const short8*)(w1 + koff);
                aF = __builtin_amdgcn_mfma_f32_16x16x32_bf16(cv.s, bf_, aF, 0, 0, 0);
                aG = __builtin_amdgcn_mfma_f32_16x16x32_bf16(cv.s, bg_, aG, 0, 0, 0);
            }
        };
        lchunk(0, b0);
        lchunk(1, b1);
        mchunk(0, b0);
        lchunk(2, b0);
        mchunk(1, b1);
        lchunk(3, b1);
        mchunk(2, b0);
        mchunk(3, b1);

        // gate math + h/Y writes
        unsigned short* hd = hbuf + ((size_t)((t + 1) & 1) << 16);
#pragma unroll
        for (int r = 0; r < 4; ++r) {
            int b = wave * 16 + quad * 4 + r;
            float f = 1.f / (1.f + __expf(-(pf[r] + aF[r] + bF)));
            float xg = pg[r] + aG[r] + bG;
            xg = fminf(fmaxf(xg, -15.f), 15.f);
            float e2 = __expf(2.f * xg);
            float g = (e2 - 1.f) / (e2 + 1.f);
            float hn = f * hr[r] + (1.f - f) * g;
            hr[r] = hn;
            unsigned short hb = f2bf(hn);
            int partner = __shfl_xor((int)hb, 1, 64);
            size_t yi = ((size_t)t * 64 + b) * 1024 + col;
            if (!(lrow & 1)) { // even lane packs (col, col+1) into one coherent u32 store
                unsigned int pk = (unsigned int)hb | ((unsigned int)partner << 16);
                __hip_atomic_store((unsigned int*)(hd + (size_t)b * 1024 + col), pk,
                                   __ATOMIC_RELAXED, __HIP_MEMORY_SCOPE_AGENT);
                if (Ybf) *(unsigned int*)(Ybf + yi) = pk; // plain store, next-kernel consumer
            }
            if (Yf32) Yf32[yi] = hn;
        }

        // ---- release: drain own stores, publish per-wave flag ----
        wait_vm0();
        if (lane == 0)
            __hip_atomic_store(&flags[w * 4 + wave], t + 1, __ATOMIC_RELAXED,
                               __HIP_MEMORY_SCOPE_AGENT);

        // prefetch next step's P under the barrier wait
        int tn = (t + 1 < TS) ? t + 1 : t;
        pload(tn, pf, pg);

        // ---- acquire: poll all 256 per-wave flags (4 per lane, two 8B coherent loads) ----
        int spins = 0;
        while (true) {
            unsigned long long v0 = ald64(&flags[lane * 4]);
            unsigned long long v1 = ald64(&flags[lane * 4 + 2]);
            int f0 = (int)v0, f1 = (int)(v0 >> 32);
            int f2 = (int)v1, f3 = (int)(v1 >> 32);
            int mn = min(min(f0, f1), min(f2, f3));
            if (__all(mn >= t + 1)) break;
            if (++spins > (1 << 17)) break; // bail loudly rather than hang
        }
        asm volatile("" ::: "memory"); // compiler barrier: keep h loads after poll
    }
}

extern "C" void kernel_launch(void* const* d_in, const int* in_sizes, int n_in,
                              void* d_out, int out_size, void* d_ws, size_t ws_size,
                              hipStream_t stream) {
    (void)in_sizes; (void)n_in; (void)out_size; (void)ws_size;
    const float* X    = (const float*)d_in[0];
    const float* ifW0 = (const float*)d_in[1];
    const float* ifB0 = (const float*)d_in[2];
    const float* hfW0 = (const float*)d_in[3];
    const float* hfB0 = (const float*)d_in[4];
    const float* igW0 = (const float*)d_in[5];
    const float* igB0 = (const float*)d_in[6];
    const float* hgW0 = (const float*)d_in[7];
    const float* hgB0 = (const float*)d_in[8];
    const float* ifW1 = (const float*)d_in[9];
    const float* ifB1 = (const float*)d_in[10];
    const float* hfW1 = (const float*)d_in[11];
    const float* hfB1 = (const float*)d_in[12];
    const float* igW1 = (const float*)d_in[13];
    const float* igB1 = (const float*)d_in[14];
    const float* hgW1 = (const float*)d_in[15];
    const float* hgB1 = (const float*)d_in[16];

    char* p = (char*)d_ws;
    auto alloc = [&](size_t bytes) {
        char* r = p; p += (bytes + 255) & ~(size_t)255; return r;
    };
    float* P            = (float*)alloc((size_t)MROWS * 2048 * 4);          // 256 MB
    unsigned short* Y0  = (unsigned short*)alloc((size_t)MROWS * 1024 * 2); // 64 MB
    unsigned short* Xb  = (unsigned short*)alloc((size_t)MROWS * 512 * 2);  // 32 MB
    unsigned short* W0c = (unsigned short*)alloc((size_t)2048 * 512 * 2);
    unsigned short* W1c = (unsigned short*)alloc((size_t)2048 * 1024 * 2);
    unsigned short* Rf0 = (unsigned short*)alloc((size_t)1024 * 1024 * 2);
    unsigned short* Rg0 = (unsigned short*)alloc((size_t)1024 * 1024 * 2);
    unsigned short* Rf1 = (unsigned short*)alloc((size_t)1024 * 1024 * 2);
    unsigned short* Rg1 = (unsigned short*)alloc((size_t)1024 * 1024 * 2);
    // contiguous zero-init region: hbufA | hbufB | flags0 | flags1
    unsigned short* hbufA = (unsigned short*)alloc((size_t)2 * 64 * 1024 * 2); // 256 KB
    unsigned short* hbufB = (unsigned short*)alloc((size_t)2 * 64 * 1024 * 2); // 256 KB
    int* flags0 = (int*)alloc(1024);
    int* flags1 = (int*)alloc(1024);
    (void)flags1;

    // ws is poisoned 0xAA every call: zero h state + barrier flags in one memset
    hipMemsetAsync(hbufA, 0, (size_t)2 * 262144 + 2048, stream);

    auto cast = [&](const float* s, unsigned short* d, size_t n) {
        int n4 = (int)(n / 4);
        cast_f32_bf16<<<dim3((n4 + 255) / 256), dim3(256), 0, stream>>>(s, d, n4);
    };
    cast(X, Xb, (size_t)MROWS * 512);
    cast(ifW0, W0c, (size_t)1024 * 512);
    cast(igW0, W0c + (size_t)1024 * 512, (size_t)1024 * 512);
    cast(ifW1, W1c, (size_t)1024 * 1024);
    cast(igW1, W1c + (size_t)1024 * 1024, (size_t)1024 * 1024);
    cast(hfW0, Rf0, (size_t)1024 * 1024);
    cast(hgW0, Rg0, (size_t)1024 * 1024);
    cast(hfW1, Rf1, (size_t)1024 * 1024);
    cast(hgW1, Rg1, (size_t)1024 * 1024);

    // layer 0
    gemm_bt_bias<<<dim3(MROWS / 128, 16), dim3(256), 0, stream>>>(Xb, W0c, ifB0, igB0, P, MROWS, 512);
    janet_scan<<<dim3(64), dim3(256), 0, stream>>>(P, Rf0, Rg0, hfB0, hgB0, hbufA, flags0, Y0, nullptr);

    // layer 1
    gemm_bt_bias<<<dim3(MROWS / 128, 16), dim3(256), 0, stream>>>(Y0, W1c, ifB1, igB1, P, MROWS, 1024);
    janet_scan<<<dim3(64), dim3(256), 0, stream>>>(P, Rf1, Rg1, hfB1, hgB1, hbufB, flags1, nullptr, (float*)d_out);
}

// Round 3
// 12227.277 us; speedup vs baseline: 1.4144x; 1.4144x over previous
//
#include <hip/hip_runtime.h>
#include <cstdint>

typedef short short8 __attribute__((ext_vector_type(8)));
typedef float floatx4 __attribute__((ext_vector_type(4)));

#define TS 512
#define BB 64
#define HD 1024
#define MROWS (TS * BB) // 32768

__device__ __forceinline__ unsigned short f2bf(float f) {
    uint32_t u = __float_as_uint(f);
    u += 0x7fffu + ((u >> 16) & 1u); // RNE
    return (unsigned short)(u >> 16);
}

__device__ __forceinline__ void wait_vm0() {
    asm volatile("s_waitcnt vmcnt(0)" ::: "memory");
}

__device__ __forceinline__ unsigned long long ald64(const void* p) {
    return __hip_atomic_load((const unsigned long long*)p, __ATOMIC_RELAXED,
                             __HIP_MEMORY_SCOPE_AGENT);
}

// ---------------- fp32 -> bf16 cast (vectorized) ----------------
__global__ __launch_bounds__(256) void cast_f32_bf16(const float* __restrict__ s,
                                                     unsigned short* __restrict__ d, int n4) {
    int i = blockIdx.x * 256 + threadIdx.x;
    if (i >= n4) return;
    float4 v = ((const float4*)s)[i];
    ushort4 o = make_ushort4(f2bf(v.x), f2bf(v.y), f2bf(v.z), f2bf(v.w));
    ((ushort4*)d)[i] = o;
}

// ---------------- input-projection GEMM ----------------
// C[M,2048] = A[M,K](bf16) * Bt[2048,K]^T + bias ; cols 0..1023 get biasF-1 (BETA), rest biasG
__global__ __launch_bounds__(256) void gemm_bt_bias(
    const unsigned short* __restrict__ A, const unsigned short* __restrict__ Bt,
    const float* __restrict__ biasF, const float* __restrict__ biasG,
    float* __restrict__ C, int M, int K)
{
    const int N = 2048;
    __shared__ unsigned short As[128 * 32];
    __shared__ unsigned short Bs[128 * 32];
    int bm = blockIdx.x * 128, bn = blockIdx.y * 128;
    int th = threadIdx.x;
    int wave = th >> 6, lane = th & 63;
    int lrow = lane & 15, quad = lane >> 4;
    int wm = (wave & 1) * 64, wn = (wave >> 1) * 64;
    const unsigned short* Ag = A + (size_t)bm * K;
    const unsigned short* Bg = Bt + (size_t)bn * K;

    floatx4 acc[4][4];
#pragma unroll
    for (int i = 0; i < 4; ++i)
#pragma unroll
        for (int j = 0; j < 4; ++j) acc[i][j] = (floatx4){0.f, 0.f, 0.f, 0.f};

    for (int k0 = 0; k0 < K; k0 += 32) {
        __syncthreads();
#pragma unroll
        for (int jj = 0; jj < 2; ++jj) {
            int c = jj * 256 + th;          // 512 16B chunks per tile
            int row = c >> 2, kk = c & 3;   // 4 chunks (32 elems) per row
            int ph = (row * 4 + (kk ^ ((row >> 1) & 3))) * 8;
            uint4 va = *(const uint4*)(Ag + (size_t)row * K + k0 + kk * 8);
            uint4 vb = *(const uint4*)(Bg + (size_t)row * K + k0 + kk * 8);
            *(uint4*)(As + ph) = va;
            *(uint4*)(Bs + ph) = vb;
        }
        __syncthreads();
        short8 af[4], bfv[4];
#pragma unroll
        for (int i = 0; i < 4; ++i) {
            int r = wm + i * 16 + lrow;
            af[i] = *(const short8*)(As + (r * 4 + (quad ^ ((r >> 1) & 3))) * 8);
        }
#pragma unroll
        for (int j = 0; j < 4; ++j) {
            int r = wn + j * 16 + lrow;
            bfv[j] = *(const short8*)(Bs + (r * 4 + (quad ^ ((r >> 1) & 3))) * 8);
        }
#pragma unroll
        for (int i = 0; i < 4; ++i)
#pragma unroll
            for (int j = 0; j < 4; ++j)
                acc[i][j] = __builtin_amdgcn_mfma_f32_16x16x32_bf16(af[i], bfv[j], acc[i][j], 0, 0, 0);
    }
#pragma unroll
    for (int j = 0; j < 4; ++j) {
        int col = bn + wn + j * 16 + lrow;
        float bias = (col < 1024) ? (biasF[col] - 1.0f) : biasG[col - 1024];
#pragma unroll
        for (int i = 0; i < 4; ++i) {
            int row0 = bm + wm + i * 16 + quad * 4;
#pragma unroll
            for (int r = 0; r < 4; ++r)
                C[(size_t)(row0 + r) * N + col] = acc[i][j][r] + bias;
        }
    }
}

// ---------------- persistent JANET recurrence ----------------
// 64 WGs x 256 threads. WG w owns hidden cols [16w,16w+16); wave v owns batch rows [16v,16v+16).
// Weights LDS-resident. Hybrid protocol:
//   release: sc1 write-through h stores -> s_waitcnt vmcnt(0) -> sc1 per-wave flag (R2, proven)
//   acquire: sc1 flag poll -> agent acquire fence (buffer_inv, cheap) -> PLAIN pipelined
//            b128 h loads (R1, proven). No per-step wbl2, no serialized atomic loads.
__global__ __launch_bounds__(256) void janet_scan(
    const float* __restrict__ P,        // [T*64, 2048]  (pf | pg), bias-BETA folded
    const unsigned short* __restrict__ Rf, // hfW bf16 [1024,1024]
    const unsigned short* __restrict__ Rg, // hgW bf16 [1024,1024]
    const float* __restrict__ hbf, const float* __restrict__ hbg,
    unsigned short* __restrict__ hbuf,  // [2][64][1024] bf16, zeroed
    int* flags,                         // [256] = 64 WG x 4 waves, zeroed
    unsigned short* __restrict__ Ybf,   // layer0 output (bf16) or null
    float* __restrict__ Yf32)           // layer1 output (fp32) or null
{
    __shared__ unsigned short Wl[2][16 * 1024]; // 64 KiB, XOR-swizzled by (n&7)
    const int w = blockIdx.x, th = threadIdx.x;
    const int wave = th >> 6, lane = th & 63;
    const int lrow = lane & 15, quad = lane >> 4;
    const int c0 = w * 16;

    // load weight slices once: 4096 16B chunks (2 gates x 16 rows x 128 chunks)
    for (int c = th; c < 4096; c += 256) {
        int g = c >> 11, n = (c >> 7) & 15, k8 = c & 127;
        const unsigned short* src = (g ? Rg : Rf) + (size_t)(c0 + n) * 1024 + k8 * 8;
        *(uint4*)(&Wl[g][(n * 128 + (k8 ^ (n & 7))) * 8]) = *(const uint4*)src;
    }
    __syncthreads();

    const int col = c0 + lrow;
    const float bF = hbf[col], bG = hbg[col];
    float hr[4] = {0.f, 0.f, 0.f, 0.f};     // fp32 master h, C-layout (b=wave*16+quad*4+r)
    const int myrow = wave * 16 + lrow;      // A-frag batch row
    const int sw = lrow & 7;
    const unsigned short* w0 = &Wl[0][lrow << 10];
    const unsigned short* w1 = &Wl[1][lrow << 10];

    // P prefetch (plain loads; P is read-once, produced by a prior kernel)
    float pf[4], pg[4];
    auto pload = [&](int t, float* pfD, float* pgD) {
        size_t pbase = ((size_t)t * 64 + wave * 16 + quad * 4) * 2048 + col;
#pragma unroll
        for (int r = 0; r < 4; ++r) {
            pfD[r] = P[pbase + (size_t)r * 2048];
            pgD[r] = P[pbase + (size_t)r * 2048 + 1024];
        }
    };
    pload(0, pf, pg);

    for (int t = 0; t < TS; ++t) {
        const unsigned short* hs =
            hbuf + ((size_t)(t & 1) << 16) + ((size_t)myrow << 10) + (quad << 3);

        // PLAIN pipelined h loads (b128), 4 chunks of 8 k-steps, double chunk-buffered
        short8 hA[8], hB[8];
        auto lchunk = [&](int c, short8* buf) {
#pragma unroll
            for (int i = 0; i < 8; ++i)
                buf[i] = *(const short8*)(hs + (((c << 3) + i) << 5));
        };
        floatx4 aF = {0.f, 0.f, 0.f, 0.f}, aG = {0.f, 0.f, 0.f, 0.f};
        auto mchunk = [&](int c, const short8* buf) {
#pragma unroll
            for (int i = 0; i < 8; ++i) {
                int ks = (c << 3) + i;
                int koff = ((((ks << 2) + quad) ^ sw) << 3);
                short8 bf_ = *(const short8*)(w0 + koff);
                short8 bg_ = *(const short8*)(w1 + koff);
                aF = __builtin_amdgcn_mfma_f32_16x16x32_bf16(buf[i], bf_, aF, 0, 0, 0);
                aG = __builtin_amdgcn_mfma_f32_16x16x32_bf16(buf[i], bg_, aG, 0, 0, 0);
            }
        };
        lchunk(0, hA);
        lchunk(1, hB);
        mchunk(0, hA);
        lchunk(2, hA);
        mchunk(1, hB);
        lchunk(3, hB);
        mchunk(2, hA);
        mchunk(3, hB);

        // gate math + h/Y writes
        unsigned short* hd = hbuf + ((size_t)((t + 1) & 1) << 16);
#pragma unroll
        for (int r = 0; r < 4; ++r) {
            int b = wave * 16 + quad * 4 + r;
            float f = 1.f / (1.f + __expf(-(pf[r] + aF[r] + bF)));
            float xg = pg[r] + aG[r] + bG;
            xg = fminf(fmaxf(xg, -15.f), 15.f);
            float e2 = __expf(2.f * xg);
            float g = (e2 - 1.f) / (e2 + 1.f);
            float hn = f * hr[r] + (1.f - f) * g;
            hr[r] = hn;
            unsigned short hb = f2bf(hn);
            int partner = __shfl_xor((int)hb, 1, 64);
            size_t yi = ((size_t)t * 64 + b) * 1024 + col;
            if (!(lrow & 1)) { // even lane packs (col, col+1) into one coherent u32 store
                unsigned int pk = (unsigned int)hb | ((unsigned int)partner << 16);
                __hip_atomic_store((unsigned int*)(hd + (size_t)b * 1024 + col), pk,
                                   __ATOMIC_RELAXED, __HIP_MEMORY_SCOPE_AGENT);
                if (Ybf) *(unsigned int*)(Ybf + yi) = pk; // plain store, next-kernel consumer
            }
            if (Yf32) Yf32[yi] = hn;
        }

        // ---- release: drain own stores, publish per-wave flag ----
        wait_vm0();
        if (lane == 0)
            __hip_atomic_store(&flags[w * 4 + wave], t + 1, __ATOMIC_RELAXED,
                               __HIP_MEMORY_SCOPE_AGENT);

        // prefetch next step's P under the barrier wait
        int tn = (t + 1 < TS) ? t + 1 : t;
        pload(tn, pf, pg);

        // ---- acquire: poll all 256 per-wave flags (4 per lane, two 8B coherent loads) ----
        int spins = 0;
        while (true) {
            unsigned long long v0 = ald64(&flags[lane * 4]);
            unsigned long long v1 = ald64(&flags[lane * 4 + 2]);
            int f0 = (int)v0, f1 = (int)(v0 >> 32);
            int f2 = (int)v1, f3 = (int)(v1 >> 32);
            int mn = min(min(f0, f1), min(f2, f3));
            if (__all(mn >= t + 1)) break;
            if (++spins > (1 << 17)) break; // bail loudly rather than hang
        }
        // invalidate stale L1/L2 h lines so the plain loads above see sc1 data (cheap:
        // buffer_inv only; the expensive wbl2 belongs to release fences, which we avoid)
        __builtin_amdgcn_fence(__ATOMIC_ACQUIRE, "agent");
    }
}

extern "C" void kernel_launch(void* const* d_in, const int* in_sizes, int n_in,
                              void* d_out, int out_size, void* d_ws, size_t ws_size,
                              hipStream_t stream) {
    (void)in_sizes; (void)n_in; (void)out_size; (void)ws_size;
    const float* X    = (const float*)d_in[0];
    const float* ifW0 = (const float*)d_in[1];
    const float* ifB0 = (const float*)d_in[2];
    const float* hfW0 = (const float*)d_in[3];
    const float* hfB0 = (const float*)d_in[4];
    const float* igW0 = (const float*)d_in[5];
    const float* igB0 = (const float*)d_in[6];
    const float* hgW0 = (const float*)d_in[7];
    const float* hgB0 = (const float*)d_in[8];
    const float* ifW1 = (const float*)d_in[9];
    const float* ifB1 = (const float*)d_in[10];
    const float* hfW1 = (const float*)d_in[11];
    const float* hfB1 = (const float*)d_in[12];
    const float* igW1 = (const float*)d_in[13];
    const float* igB1 = (const float*)d_in[14];
    const float* hgW1 = (const float*)d_in[15];
    const float* hgB1 = (const float*)d_in[16];

    char* p = (char*)d_ws;
    auto alloc = [&](size_t bytes) {
        char* r = p; p += (bytes + 255) & ~(size_t)255; return r;
    };
    float* P            = (float*)alloc((size_t)MROWS * 2048 * 4);          // 256 MB
    unsigned short* Y0  = (unsigned short*)alloc((size_t)MROWS * 1024 * 2); // 64 MB
    unsigned short* Xb  = (unsigned short*)alloc((size_t)MROWS * 512 * 2);  // 32 MB
    unsigned short* W0c = (unsigned short*)alloc((size_t)2048 * 512 * 2);
    unsigned short* W1c = (unsigned short*)alloc((size_t)2048 * 1024 * 2);
    unsigned short* Rf0 = (unsigned short*)alloc((size_t)1024 * 1024 * 2);
    unsigned short* Rg0 = (unsigned short*)alloc((size_t)1024 * 1024 * 2);
    unsigned short* Rf1 = (unsigned short*)alloc((size_t)1024 * 1024 * 2);
    unsigned short* Rg1 = (unsigned short*)alloc((size_t)1024 * 1024 * 2);
    // contiguous zero-init region: hbufA | hbufB | flags0 | flags1
    unsigned short* hbufA = (unsigned short*)alloc((size_t)2 * 64 * 1024 * 2); // 256 KB
    unsigned short* hbufB = (unsigned short*)alloc((size_t)2 * 64 * 1024 * 2); // 256 KB
    int* flags0 = (int*)alloc(1024);
    int* flags1 = (int*)alloc(1024);
    (void)flags1;

    // ws is poisoned 0xAA every call: zero h state + barrier flags in one memset
    hipMemsetAsync(hbufA, 0, (size_t)2 * 262144 + 2048, stream);

    auto cast = [&](const float* s, unsigned short* d, size_t n) {
        int n4 = (int)(n / 4);
        cast_f32_bf16<<<dim3((n4 + 255) / 256), dim3(256), 0, stream>>>(s, d, n4);
    };
    cast(X, Xb, (size_t)MROWS * 512);
    cast(ifW0, W0c, (size_t)1024 * 512);
    cast(igW0, W0c + (size_t)1024 * 512, (size_t)1024 * 512);
    cast(ifW1, W1c, (size_t)1024 * 1024);
    cast(igW1, W1c + (size_t)1024 * 1024, (size_t)1024 * 1024);
    cast(hfW0, Rf0, (size_t)1024 * 1024);
    cast(hgW0, Rg0, (size_t)1024 * 1024);
    cast(hfW1, Rf1, (size_t)1024 * 1024);
    cast(hgW1, Rg1, (size_t)1024 * 1024);

    // layer 0
    gemm_bt_bias<<<dim3(MROWS / 128, 16), dim3(256), 0, stream>>>(Xb, W0c, ifB0, igB0, P, MROWS, 512);
    janet_scan<<<dim3(64), dim3(256), 0, stream>>>(P, Rf0, Rg0, hfB0, hgB0, hbufA, flags0, Y0, nullptr);

    // layer 1
    gemm_bt_bias<<<dim3(MROWS / 128, 16), dim3(256), 0, stream>>>(Y0, W1c, ifB1, igB1, P, MROWS, 1024);
    janet_scan<<<dim3(64), dim3(256), 0, stream>>>(P, Rf1, Rg1, hfB1, hgB1, hbufB, flags1, nullptr, (float*)d_out);
}